// Round 4
// baseline (144.926 us; speedup 1.0000x reference)
//
#include <hip/hip_runtime.h>
#include <hip/hip_bf16.h>

#define E_ 8
#define D_ 1024
#define H_ 4096
#define T_ 512
#define A_ 1024  // total assignments = T_ * top_k
#define BM_ 192  // covers count<=192 in one pass (6.5 sigma of Binomial(512,1/4))

typedef __attribute__((ext_vector_type(8))) short bf16x8;
typedef __attribute__((ext_vector_type(4))) float f32x4;

__device__ __forceinline__ unsigned short f2bf(float f) {
  __hip_bfloat16 h = __float2bfloat16(f);
  return *reinterpret_cast<unsigned short*>(&h);
}

__device__ __forceinline__ bf16x8 pk8(float4 a, float4 b) {
  bf16x8 r;
  r[0] = (short)f2bf(a.x); r[1] = (short)f2bf(a.y);
  r[2] = (short)f2bf(a.z); r[3] = (short)f2bf(a.w);
  r[4] = (short)f2bf(b.x); r[5] = (short)f2bf(b.y);
  r[6] = (short)f2bf(b.z); r[7] = (short)f2bf(b.w);
  return r;
}

// async global->LDS, 16B per lane; dest = wave-uniform base + lane*16
__device__ __forceinline__ void gl16(const void* g, void* l) {
  __builtin_amdgcn_global_load_lds(
      (const __attribute__((address_space(1))) unsigned int*)g,
      (__attribute__((address_space(3))) unsigned int*)l, 16, 0, 0);
}

// ---------------- Router: logits -> softmax -> top2 -> renorm; x -> bf16 ----
__global__ void moe_router(const float* __restrict__ x,
                           const float* __restrict__ gw,
                           unsigned short* __restrict__ xb,
                           int* __restrict__ sel,
                           float* __restrict__ wtop) {
  const int t = blockIdx.x;
  const int lane = threadIdx.x;  // 64
  const float* xr = x + (size_t)t * D_;

  float4 xv[4];
#pragma unroll
  for (int i = 0; i < 4; ++i) xv[i] = *reinterpret_cast<const float4*>(xr + (i * 64 + lane) * 4);
#pragma unroll
  for (int i = 0; i < 4; ++i) {
    ushort4 u;
    u.x = f2bf(xv[i].x); u.y = f2bf(xv[i].y); u.z = f2bf(xv[i].z); u.w = f2bf(xv[i].w);
    *reinterpret_cast<ushort4*>(xb + (size_t)t * D_ + (i * 64 + lane) * 4) = u;
  }

  float lg[E_];
  for (int e = 0; e < E_; ++e) {
    const float* g = gw + (size_t)e * D_;
    float p = 0.f;
#pragma unroll
    for (int i = 0; i < 4; ++i) {
      float4 gv = *reinterpret_cast<const float4*>(g + (i * 64 + lane) * 4);
      p += xv[i].x * gv.x + xv[i].y * gv.y + xv[i].z * gv.z + xv[i].w * gv.w;
    }
#pragma unroll
    for (int off = 32; off; off >>= 1) p += __shfl_xor(p, off);
    lg[e] = p;
  }
  if (lane == 0) {
    float m = lg[0];
    for (int e = 1; e < E_; ++e) m = fmaxf(m, lg[e]);
    float pr[E_];
    float s = 0.f;
    for (int e = 0; e < E_; ++e) { pr[e] = __expf(lg[e] - m); s += pr[e]; }
    const float inv = 1.f / s;
    for (int e = 0; e < E_; ++e) pr[e] *= inv;
    float v0 = -1.f, v1 = -1.f; int i0 = 0, i1 = 0;
    for (int e = 0; e < E_; ++e) {
      float p = pr[e];
      if (p > v0)      { v1 = v0; i1 = i0; v0 = p; i0 = e; }
      else if (p > v1) { v1 = p; i1 = e; }
    }
    const float s2 = 1.f / (v0 + v1);
    sel[2 * t] = i0; sel[2 * t + 1] = i1;
    wtop[2 * t] = v0 * s2; wtop[2 * t + 1] = v1 * s2;
  }
}

// ---------------- Compaction: deterministic, order-preserving ---------------
__global__ void moe_compact(const int* __restrict__ sel,
                            const float* __restrict__ wtop,
                            int* __restrict__ counts,
                            int* __restrict__ offsets,
                            int* __restrict__ tok,
                            int* __restrict__ slotof,
                            float* __restrict__ coef) {
  const int tid = threadIdx.x;  // 512 = 8 waves; wave = expert
  const int e = tid >> 6;
  const int lane = tid & 63;
  __shared__ int cnt[E_], offs[E_];

  int base = 0;
  for (int c = 0; c < T_ / 64; ++c) {
    const int t = c * 64 + lane;
    const bool f = (sel[2 * t] == e) || (sel[2 * t + 1] == e);
    base += __popcll(__ballot(f));
  }
  if (lane == 0) cnt[e] = base;
  __syncthreads();
  if (tid == 0) {
    int o = 0;
    for (int i = 0; i < E_; ++i) { offs[i] = o; o += cnt[i]; }
  }
  __syncthreads();
  if (lane == 0) { counts[e] = cnt[e]; offsets[e] = offs[e]; }

  int pos = offs[e];
  for (int c = 0; c < T_ / 64; ++c) {
    const int t = c * 64 + lane;
    const int s0 = sel[2 * t], s1 = sel[2 * t + 1];
    const bool f = (s0 == e) || (s1 == e);
    unsigned long long b = __ballot(f);
    const int myp = pos + __popcll(b & ((1ull << lane) - 1ull));
    if (f) {
      const int k = (s0 == e) ? 0 : 1;
      tok[myp] = t;
      slotof[2 * t + k] = myp;
      coef[myp] = wtop[2 * t + k];
    }
    pos += __popcll(b);
  }
}

// ---------------- FFN kernels: 2-phase gl_lds double-buffered pipeline ------
// BK=32. A: bf16 [192][32] linear+XOR-swizzled. B: fp32 [64][32] swizzled,
// converted to bf16 at fragment read. 4 waves split M (48 rows each).
// LDS dest of gl_lds is linear; swizzle applied via per-lane SOURCE column
// (store side) and XOR'd read address (read side) — rule #21.

#define STAGE1(buf, kt) do {                                                  \
    _Pragma("unroll")                                                         \
    for (int j = 0; j < 3; ++j)                                               \
      gl16(asrc[j] + (kt), &As[buf][(j * 4 + wid) * 512]);                    \
    _Pragma("unroll")                                                         \
    for (int j = 0; j < 2; ++j) {                                             \
      gl16(b1src[j] + (kt), &B1s[buf][(j * 4 + wid) * 256]);                  \
      gl16(b3src[j] + (kt), &B3s[buf][(j * 4 + wid) * 256]);                  \
    }                                                                         \
  } while (0)

__launch_bounds__(256, 2)
__global__ void moe_ffn1(const unsigned short* __restrict__ xb,
                         const float* __restrict__ w1,
                         const float* __restrict__ w3,
                         const int* __restrict__ counts,
                         const int* __restrict__ offsets,
                         const int* __restrict__ tok,
                         unsigned short* __restrict__ act) {
  const int bid = blockIdx.x;
  const int hg = bid & 63;
  const int e = bid >> 6;
  const int count = counts[e];
  const int off = offsets[e];
  const int hbase = hg * 64;

  __shared__ unsigned short As[2][BM_ * 32];  // 2 x 12 KB
  __shared__ float B1s[2][64 * 32];           // 2 x 8 KB
  __shared__ float B3s[2][64 * 32];           // 2 x 8 KB

  const int tid = threadIdx.x;
  const int lane = tid & 63, wid = tid >> 6;
  const int lr = lane & 15, kg = lane >> 4;
  const int wm = wid * 48;

  // Staging source columns (pre-swizzled so linear LDS dest = swizzled layout)
  const int cA = (((lane & 3) ^ ((lane >> 3) & 3)) << 3);  // u16 elems
  const int cB = (((lane & 7) ^ ((lane >> 3) & 7)) << 2);  // f32 elems
  const float* b1src[2];
  const float* b3src[2];
#pragma unroll
  for (int j = 0; j < 2; ++j) {
    const int row = (j * 4 + wid) * 8 + (lane >> 3);
    b1src[j] = w1 + ((size_t)e * H_ + hbase + row) * D_ + cB;
    b3src[j] = w3 + ((size_t)e * H_ + hbase + row) * D_ + cB;
  }

  for (int m0 = 0; m0 < count; m0 += BM_) {
    const unsigned short* asrc[3];
#pragma unroll
    for (int j = 0; j < 3; ++j) {
      const int row = (j * 4 + wid) * 16 + (lane >> 2);
      const int cr = (m0 + row < count) ? (m0 + row) : (count - 1);
      asrc[j] = xb + (size_t)tok[off + cr] * D_ + cA;
    }
    const int q = count - m0 - wm;
    const int mfn = (q <= 0) ? 0 : ((q + 15) >> 4 < 3 ? (q + 15) >> 4 : 3);

    f32x4 acc1[3][4] = {};
    f32x4 acc3[3][4] = {};

    STAGE1(0, 0);
    __syncthreads();

    int cur = 0;
    const int pa = ((kg ^ ((lr >> 1) & 3)) << 3);
    const int q0 = (((kg * 2) ^ (lr & 7)) << 2);
    const int q1 = (((kg * 2 + 1) ^ (lr & 7)) << 2);
    for (int it = 0; it < 32; ++it) {
      if (it + 1 < 32) STAGE1(cur ^ 1, (it + 1) * 32);
      bf16x8 af[3];
#pragma unroll
      for (int mf = 0; mf < 3; ++mf)
        af[mf] = *reinterpret_cast<const bf16x8*>(&As[cur][(wm + mf * 16 + lr) * 32 + pa]);
#pragma unroll
      for (int nf = 0; nf < 4; ++nf) {
        const int rb = (nf * 16 + lr) * 32;
        bf16x8 b1f = pk8(*reinterpret_cast<const float4*>(&B1s[cur][rb + q0]),
                         *reinterpret_cast<const float4*>(&B1s[cur][rb + q1]));
        bf16x8 b3f = pk8(*reinterpret_cast<const float4*>(&B3s[cur][rb + q0]),
                         *reinterpret_cast<const float4*>(&B3s[cur][rb + q1]));
#pragma unroll
        for (int mf = 0; mf < 3; ++mf)
          if (mf < mfn) {
            acc1[mf][nf] = __builtin_amdgcn_mfma_f32_16x16x32_bf16(af[mf], b1f, acc1[mf][nf], 0, 0, 0);
            acc3[mf][nf] = __builtin_amdgcn_mfma_f32_16x16x32_bf16(af[mf], b3f, acc3[mf][nf], 0, 0, 0);
          }
      }
      if (it + 1 < 32) { __syncthreads(); cur ^= 1; }
    }

    // Epilogue: silu(h1)*h3 -> bf16 act
#pragma unroll
    for (int mf = 0; mf < 3; ++mf) {
#pragma unroll
      for (int r = 0; r < 4; ++r) {
        const int mrow = m0 + wm + mf * 16 + kg * 4 + r;
        if (mrow < count) {
          const size_t rb = (size_t)(off + mrow) * H_;
#pragma unroll
          for (int nf = 0; nf < 4; ++nf) {
            const float h1 = acc1[mf][nf][r];
            const float h3 = acc3[mf][nf][r];
            const float a = h1 / (1.f + __expf(-h1)) * h3;
            act[rb + hbase + nf * 16 + lr] = f2bf(a);
          }
        }
      }
    }
    __syncthreads();  // protect LDS before next m0 pass
  }
}

#define STAGE2(buf, kt) do {                                                  \
    _Pragma("unroll")                                                         \
    for (int j = 0; j < 3; ++j)                                               \
      gl16(asrc[j] + (kt), &As[buf][(j * 4 + wid) * 512]);                    \
    _Pragma("unroll")                                                         \
    for (int j = 0; j < 2; ++j)                                               \
      gl16(bsrc[j] + (kt), &Bs[buf][(j * 4 + wid) * 256]);                    \
  } while (0)

__launch_bounds__(256, 2)
__global__ void moe_ffn2(const unsigned short* __restrict__ act,
                         const float* __restrict__ w2,
                         const int* __restrict__ counts,
                         const int* __restrict__ offsets,
                         const float* __restrict__ coef,
                         float* __restrict__ part,
                         int kschunk) {
  const int bid = blockIdx.x;
  const int ks = bid >> 7;
  const int e = (bid >> 4) & 7;
  const int dg = bid & 15;
  const int count = counts[e];
  const int off = offsets[e];
  const int dbase = dg * 64;
  const int kbase = ks * kschunk;
  const int nit = kschunk >> 5;

  __shared__ unsigned short As[2][BM_ * 32];
  __shared__ float Bs[2][64 * 32];

  const int tid = threadIdx.x;
  const int lane = tid & 63, wid = tid >> 6;
  const int lr = lane & 15, kg = lane >> 4;
  const int wm = wid * 48;

  const int cA = (((lane & 3) ^ ((lane >> 3) & 3)) << 3);
  const int cB = (((lane & 7) ^ ((lane >> 3) & 7)) << 2);
  const float* bsrc[2];
#pragma unroll
  for (int j = 0; j < 2; ++j) {
    const int row = (j * 4 + wid) * 8 + (lane >> 3);
    bsrc[j] = w2 + ((size_t)e * D_ + dbase + row) * H_ + kbase + cB;
  }

  for (int m0 = 0; m0 < count; m0 += BM_) {
    const unsigned short* asrc[3];
#pragma unroll
    for (int j = 0; j < 3; ++j) {
      const int row = (j * 4 + wid) * 16 + (lane >> 2);
      const int cr = (m0 + row < count) ? (m0 + row) : (count - 1);
      asrc[j] = act + (size_t)(off + cr) * H_ + kbase + cA;
    }
    const int q = count - m0 - wm;
    const int mfn = (q <= 0) ? 0 : ((q + 15) >> 4 < 3 ? (q + 15) >> 4 : 3);

    f32x4 acc[3][4] = {};

    STAGE2(0, 0);
    __syncthreads();

    int cur = 0;
    const int pa = ((kg ^ ((lr >> 1) & 3)) << 3);
    const int q0 = (((kg * 2) ^ (lr & 7)) << 2);
    const int q1 = (((kg * 2 + 1) ^ (lr & 7)) << 2);
    for (int it = 0; it < nit; ++it) {
      if (it + 1 < nit) STAGE2(cur ^ 1, (it + 1) * 32);
      bf16x8 af[3];
#pragma unroll
      for (int mf = 0; mf < 3; ++mf)
        af[mf] = *reinterpret_cast<const bf16x8*>(&As[cur][(wm + mf * 16 + lr) * 32 + pa]);
#pragma unroll
      for (int nf = 0; nf < 4; ++nf) {
        const int rb = (nf * 16 + lr) * 32;
        bf16x8 bf = pk8(*reinterpret_cast<const float4*>(&Bs[cur][rb + q0]),
                        *reinterpret_cast<const float4*>(&Bs[cur][rb + q1]));
#pragma unroll
        for (int mf = 0; mf < 3; ++mf)
          if (mf < mfn)
            acc[mf][nf] = __builtin_amdgcn_mfma_f32_16x16x32_bf16(af[mf], bf, acc[mf][nf], 0, 0, 0);
      }
      if (it + 1 < nit) { __syncthreads(); cur ^= 1; }
    }

#pragma unroll
    for (int mf = 0; mf < 3; ++mf) {
#pragma unroll
      for (int r = 0; r < 4; ++r) {
        const int mrow = m0 + wm + mf * 16 + kg * 4 + r;
        if (mrow < count) {
          const float cf = coef[off + mrow];
          float* prow = part + ((size_t)ks * A_ + off + mrow) * D_;
#pragma unroll
          for (int nf = 0; nf < 4; ++nf)
            prow[dbase + nf * 16 + lr] = cf * acc[mf][nf][r];
        }
      }
    }
    __syncthreads();
  }
}

// out[t] = sum over (ksn x 2 slots) partials in fixed order -> deterministic
__global__ void moe_combine(const float* __restrict__ part,
                            const int* __restrict__ slotof,
                            float* __restrict__ out,
                            int ksn) {
  const int t = blockIdx.x;
  const int i = threadIdx.x;  // 256 threads, float4 each
  const int g0 = slotof[2 * t], g1 = slotof[2 * t + 1];
  float4 o = make_float4(0.f, 0.f, 0.f, 0.f);
  for (int ks = 0; ks < ksn; ++ks) {
    const float* p = part + (size_t)ks * A_ * D_;
    float4 a = reinterpret_cast<const float4*>(p + (size_t)g0 * D_)[i];
    float4 b = reinterpret_cast<const float4*>(p + (size_t)g1 * D_)[i];
    o.x += a.x + b.x; o.y += a.y + b.y; o.z += a.z + b.z; o.w += a.w + b.w;
  }
  reinterpret_cast<float4*>(out + (size_t)t * D_)[i] = o;
}

extern "C" void kernel_launch(void* const* d_in, const int* in_sizes, int n_in,
                              void* d_out, int out_size, void* d_ws, size_t ws_size,
                              hipStream_t stream) {
  const float* x  = (const float*)d_in[0];
  const float* gw = (const float*)d_in[1];
  const float* w1 = (const float*)d_in[2];
  const float* w3 = (const float*)d_in[3];
  const float* w2 = (const float*)d_in[4];
  float* out = (float*)d_out;

  char* ws = (char*)d_ws;
  const size_t SM   = 32768;
  const size_t ACT  = (size_t)A_ * H_ * 2;   // 8 MB bf16
  const size_t XB   = (size_t)T_ * D_ * 2;   // 1 MB bf16
  const size_t P1   = (size_t)A_ * D_ * 4;   // 4 MB fp32 per K-split

  char* sm = ws;
  unsigned short* act = (unsigned short*)(ws + SM);
  unsigned short* xb  = (unsigned short*)(ws + SM + ACT);
  float* part         = (float*)(ws + SM + ACT + XB);
  const size_t base = SM + ACT + XB;
  const int ksn = (ws_size >= base + 4 * P1) ? 4 : (ws_size >= base + 2 * P1) ? 2 : 1;

  int*   sel     = (int*)  (sm);
  float* wtop    = (float*)(sm + 4096);
  int*   counts  = (int*)  (sm + 8192);
  int*   offsets = (int*)  (sm + 8192 + 64);
  int*   tokl    = (int*)  (sm + 12288);
  int*   slotof  = (int*)  (sm + 16384);
  float* coef    = (float*)(sm + 20480);

  moe_router <<<T_, 64, 0, stream>>>(x, gw, xb, sel, wtop);
  moe_compact<<<1, 512, 0, stream>>>(sel, wtop, counts, offsets, tokl, slotof, coef);
  moe_ffn1   <<<E_ * 64, 256, 0, stream>>>(xb, w1, w3, counts, offsets, tokl, act);
  moe_ffn2   <<<128 * ksn, 256, 0, stream>>>(act, w2, counts, offsets, coef, part, H_ / ksn);
  moe_combine<<<T_, 256, 0, stream>>>(part, slotof, out, ksn);
}

// Round 5
// 143.293 us; speedup vs baseline: 1.0114x; 1.0114x over previous
//
#include <hip/hip_runtime.h>
#include <hip/hip_bf16.h>

#define E_ 8
#define D_ 1024
#define H_ 4096
#define T_ 512
#define A_ 1024  // total assignments = T_ * top_k
#define BM_ 192  // covers count<=192 in one pass (6.5 sigma of Binomial(512,1/4))
#define NBUF 3

typedef __attribute__((ext_vector_type(8))) short bf16x8;
typedef __attribute__((ext_vector_type(4))) float f32x4;

__device__ __forceinline__ unsigned short f2bf(float f) {
  __hip_bfloat16 h = __float2bfloat16(f);
  return *reinterpret_cast<unsigned short*>(&h);
}

__device__ __forceinline__ bf16x8 pk8(float4 a, float4 b) {
  bf16x8 r;
  r[0] = (short)f2bf(a.x); r[1] = (short)f2bf(a.y);
  r[2] = (short)f2bf(a.z); r[3] = (short)f2bf(a.w);
  r[4] = (short)f2bf(b.x); r[5] = (short)f2bf(b.y);
  r[6] = (short)f2bf(b.z); r[7] = (short)f2bf(b.w);
  return r;
}

// async global->LDS, 16B per lane; dest = wave-uniform base + lane*16
__device__ __forceinline__ void gl16(const void* g, void* l) {
  __builtin_amdgcn_global_load_lds(
      (const __attribute__((address_space(1))) unsigned int*)g,
      (__attribute__((address_space(3))) unsigned int*)l, 16, 0, 0);
}

// ---------------- Router ----------------------------------------------------
__global__ void moe_router(const float* __restrict__ x,
                           const float* __restrict__ gw,
                           unsigned short* __restrict__ xb,
                           int* __restrict__ sel,
                           float* __restrict__ wtop) {
  const int t = blockIdx.x;
  const int lane = threadIdx.x;  // 64
  const float* xr = x + (size_t)t * D_;

  float4 xv[4];
#pragma unroll
  for (int i = 0; i < 4; ++i) xv[i] = *reinterpret_cast<const float4*>(xr + (i * 64 + lane) * 4);
#pragma unroll
  for (int i = 0; i < 4; ++i) {
    ushort4 u;
    u.x = f2bf(xv[i].x); u.y = f2bf(xv[i].y); u.z = f2bf(xv[i].z); u.w = f2bf(xv[i].w);
    *reinterpret_cast<ushort4*>(xb + (size_t)t * D_ + (i * 64 + lane) * 4) = u;
  }

  float lg[E_];
  for (int e = 0; e < E_; ++e) {
    const float* g = gw + (size_t)e * D_;
    float p = 0.f;
#pragma unroll
    for (int i = 0; i < 4; ++i) {
      float4 gv = *reinterpret_cast<const float4*>(g + (i * 64 + lane) * 4);
      p += xv[i].x * gv.x + xv[i].y * gv.y + xv[i].z * gv.z + xv[i].w * gv.w;
    }
#pragma unroll
    for (int off = 32; off; off >>= 1) p += __shfl_xor(p, off);
    lg[e] = p;
  }
  if (lane == 0) {
    float m = lg[0];
    for (int e = 1; e < E_; ++e) m = fmaxf(m, lg[e]);
    float pr[E_];
    float s = 0.f;
    for (int e = 0; e < E_; ++e) { pr[e] = __expf(lg[e] - m); s += pr[e]; }
    const float inv = 1.f / s;
    for (int e = 0; e < E_; ++e) pr[e] *= inv;
    float v0 = -1.f, v1 = -1.f; int i0 = 0, i1 = 0;
    for (int e = 0; e < E_; ++e) {
      float p = pr[e];
      if (p > v0)      { v1 = v0; i1 = i0; v0 = p; i0 = e; }
      else if (p > v1) { v1 = p; i1 = e; }
    }
    const float s2 = 1.f / (v0 + v1);
    sel[2 * t] = i0; sel[2 * t + 1] = i1;
    wtop[2 * t] = v0 * s2; wtop[2 * t + 1] = v1 * s2;
  }
}

// ---------------- Compaction: deterministic, order-preserving ---------------
__global__ void moe_compact(const int* __restrict__ sel,
                            const float* __restrict__ wtop,
                            int* __restrict__ counts,
                            int* __restrict__ offsets,
                            int* __restrict__ tok,
                            int* __restrict__ slotof,
                            float* __restrict__ coef) {
  const int tid = threadIdx.x;  // 512 = 8 waves; wave = expert
  const int e = tid >> 6;
  const int lane = tid & 63;
  __shared__ int cnt[E_], offs[E_];

  int base = 0;
  for (int c = 0; c < T_ / 64; ++c) {
    const int t = c * 64 + lane;
    const bool f = (sel[2 * t] == e) || (sel[2 * t + 1] == e);
    base += __popcll(__ballot(f));
  }
  if (lane == 0) cnt[e] = base;
  __syncthreads();
  if (tid == 0) {
    int o = 0;
    for (int i = 0; i < E_; ++i) { offs[i] = o; o += cnt[i]; }
  }
  __syncthreads();
  if (lane == 0) { counts[e] = cnt[e]; offsets[e] = offs[e]; }

  int pos = offs[e];
  for (int c = 0; c < T_ / 64; ++c) {
    const int t = c * 64 + lane;
    const int s0 = sel[2 * t], s1 = sel[2 * t + 1];
    const bool f = (s0 == e) || (s1 == e);
    unsigned long long b = __ballot(f);
    const int myp = pos + __popcll(b & ((1ull << lane) - 1ull));
    if (f) {
      const int k = (s0 == e) ? 0 : 1;
      tok[myp] = t;
      slotof[2 * t + k] = myp;
      coef[myp] = wtop[2 * t + k];
    }
    pos += __popcll(b);
  }
}

// ---------------- FFN kernels: 3-deep counted-vmcnt pipeline ----------------
// B (weights, fp32) staged via gl_lds into 3 LDS buffers; per-iter:
//   s_waitcnt vmcnt(N) (counted, never full drain) ; raw s_barrier ;
//   A-frag loads (global, L2-resident) ; STAGE(t+2) ; ds_read B + cvt + MFMA.
// Per-wave vmcnt ledger (4 gl16/stage + 3 A-loads/iter): steady N=7,
// first iter N=4, last iter N=3.
// B LDS row quad-swizzle: store quad q of row r at q^(r&7); gl_lds writes
// linearly so the source column is pre-swizzled (rule #21), read XORs back.

#define WAITS(it, nit)                                                        \
    if ((it) == 0)              asm volatile("s_waitcnt vmcnt(4)" ::: "memory"); \
    else if ((it) == (nit) - 1) asm volatile("s_waitcnt vmcnt(3)" ::: "memory"); \
    else                        asm volatile("s_waitcnt vmcnt(7)" ::: "memory"); \
    __builtin_amdgcn_s_barrier();                                             \
    __builtin_amdgcn_sched_barrier(0);

#define STAGE1(s, kt) do {                                                    \
    gl16(b1src[0] + (kt), &B1s[s][wid * 256]);                                \
    gl16(b1src[1] + (kt), &B1s[s][1024 + wid * 256]);                         \
    gl16(b3src[0] + (kt), &B3s[s][wid * 256]);                                \
    gl16(b3src[1] + (kt), &B3s[s][1024 + wid * 256]);                         \
  } while (0)

__launch_bounds__(256, 3)
__global__ void moe_ffn1(const unsigned short* __restrict__ xb,
                         const float* __restrict__ w1,
                         const float* __restrict__ w3,
                         const int* __restrict__ counts,
                         const int* __restrict__ offsets,
                         const int* __restrict__ tok,
                         unsigned short* __restrict__ act) {
  const int bid = blockIdx.x;
  const int e = bid & 7;        // XCD-pinned: same expert -> same XCD L2
  const int hg = bid >> 3;      // 64 h-groups of 64 cols
  const int count = counts[e];
  const int off = offsets[e];
  const int hbase = hg * 64;

  __shared__ float B1s[NBUF][64 * 32];  // 3 x 8 KB
  __shared__ float B3s[NBUF][64 * 32];  // 3 x 8 KB

  const int tid = threadIdx.x;
  const int lane = tid & 63, wid = tid >> 6;
  const int lr = lane & 15, kg = lane >> 4;
  const int wm = wid * 48;

  // staging source (pre-swizzled column quad)
  const int cB = (((lane & 7) ^ (lane >> 3)) << 2);
  const float* b1src[2];
  const float* b3src[2];
#pragma unroll
  for (int j = 0; j < 2; ++j) {
    const int row = (j * 4 + wid) * 8 + (lane >> 3);
    b1src[j] = w1 + ((size_t)e * H_ + hbase + row) * D_ + cB;
    b3src[j] = w3 + ((size_t)e * H_ + hbase + row) * D_ + cB;
  }
  // swizzled read offsets (float units)
  const int q0 = (((2 * kg) ^ (lr & 7)) << 2);
  const int q1 = (((2 * kg + 1) ^ (lr & 7)) << 2);

  for (int m0 = 0; m0 < count; m0 += BM_) {
    const unsigned short* ap[3];
#pragma unroll
    for (int mf = 0; mf < 3; ++mf) {
      const int row = m0 + wm + mf * 16 + lr;
      const int cr = (row < count) ? row : (count - 1);
      ap[mf] = xb + (size_t)tok[off + cr] * D_ + kg * 8;
    }
    const int qq = count - m0 - wm;
    const int mfn = (qq <= 0) ? 0 : ((qq + 15) >> 4 < 3 ? (qq + 15) >> 4 : 3);

    f32x4 acc1[3][4] = {};
    f32x4 acc3[3][4] = {};

    STAGE1(0, 0);
    STAGE1(1, 32);

    int cur = 0;
    for (int it = 0; it < 32; ++it) {
      WAITS(it, 32);

      bf16x8 af[3];
#pragma unroll
      for (int mf = 0; mf < 3; ++mf)
        af[mf] = *reinterpret_cast<const bf16x8*>(ap[mf] + it * 32);

      if (it + 2 < 32) {
        int s2 = cur + 2; if (s2 >= NBUF) s2 -= NBUF;
        STAGE1(s2, (it + 2) * 32);
      }

#pragma unroll
      for (int nf = 0; nf < 4; ++nf) {
        const int rb = (nf * 16 + lr) * 32;
        bf16x8 b1f = pk8(*reinterpret_cast<const float4*>(&B1s[cur][rb + q0]),
                         *reinterpret_cast<const float4*>(&B1s[cur][rb + q1]));
        bf16x8 b3f = pk8(*reinterpret_cast<const float4*>(&B3s[cur][rb + q0]),
                         *reinterpret_cast<const float4*>(&B3s[cur][rb + q1]));
#pragma unroll
        for (int mf = 0; mf < 3; ++mf)
          if (mf < mfn) {
            acc1[mf][nf] = __builtin_amdgcn_mfma_f32_16x16x32_bf16(af[mf], b1f, acc1[mf][nf], 0, 0, 0);
            acc3[mf][nf] = __builtin_amdgcn_mfma_f32_16x16x32_bf16(af[mf], b3f, acc3[mf][nf], 0, 0, 0);
          }
      }
      ++cur; if (cur >= NBUF) cur -= NBUF;
    }

    // Epilogue: silu(h1)*h3 -> bf16 act
#pragma unroll
    for (int mf = 0; mf < 3; ++mf) {
#pragma unroll
      for (int r = 0; r < 4; ++r) {
        const int mrow = m0 + wm + mf * 16 + kg * 4 + r;
        if (mrow < count) {
          const size_t rb = (size_t)(off + mrow) * H_;
#pragma unroll
          for (int nf = 0; nf < 4; ++nf) {
            const float h1 = acc1[mf][nf][r];
            const float h3 = acc3[mf][nf][r];
            const float a = h1 / (1.f + __expf(-h1)) * h3;
            act[rb + hbase + nf * 16 + lr] = f2bf(a);
          }
        }
      }
    }
    __syncthreads();  // all reads done before any re-stage in next m0 pass
  }
}

#define STAGE2(s, kt) do {                                                    \
    gl16(bsrc[0] + (kt), &Bs[s][wid * 256]);                                  \
    gl16(bsrc[1] + (kt), &Bs[s][1024 + wid * 256]);                           \
  } while (0)

__launch_bounds__(256, 4)
__global__ void moe_ffn2(const unsigned short* __restrict__ act,
                         const float* __restrict__ w2,
                         const int* __restrict__ counts,
                         const int* __restrict__ offsets,
                         const float* __restrict__ coef,
                         float* __restrict__ part,
                         int kschunk) {
  const int bid = blockIdx.x;
  const int e = bid & 7;        // XCD-pinned
  const int r2 = bid >> 3;
  const int dg = r2 & 15;
  const int ks = r2 >> 4;
  const int count = counts[e];
  const int off = offsets[e];
  const int dbase = dg * 64;
  const int kbase = ks * kschunk;
  const int nit = kschunk >> 5;

  __shared__ float Bs[NBUF][64 * 32];  // 3 x 8 KB

  const int tid = threadIdx.x;
  const int lane = tid & 63, wid = tid >> 6;
  const int lr = lane & 15, kg = lane >> 4;
  const int wm = wid * 48;

  const int cB = (((lane & 7) ^ (lane >> 3)) << 2);
  const float* bsrc[2];
#pragma unroll
  for (int j = 0; j < 2; ++j) {
    const int row = (j * 4 + wid) * 8 + (lane >> 3);
    bsrc[j] = w2 + ((size_t)e * D_ + dbase + row) * H_ + kbase + cB;
  }
  const int q0 = (((2 * kg) ^ (lr & 7)) << 2);
  const int q1 = (((2 * kg + 1) ^ (lr & 7)) << 2);

  for (int m0 = 0; m0 < count; m0 += BM_) {
    const unsigned short* ap[3];
#pragma unroll
    for (int mf = 0; mf < 3; ++mf) {
      const int row = m0 + wm + mf * 16 + lr;
      const int cr = (row < count) ? row : (count - 1);
      ap[mf] = act + (size_t)(off + cr) * H_ + kbase + kg * 8;
    }
    const int qq = count - m0 - wm;
    const int mfn = (qq <= 0) ? 0 : ((qq + 15) >> 4 < 3 ? (qq + 15) >> 4 : 3);

    f32x4 acc[3][4] = {};

    STAGE2(0, 0);
    STAGE2(1, 32);

    int cur = 0;
    for (int it = 0; it < nit; ++it) {
      WAITS(it, nit);

      bf16x8 af[3];
#pragma unroll
      for (int mf = 0; mf < 3; ++mf)
        af[mf] = *reinterpret_cast<const bf16x8*>(ap[mf] + it * 32);

      if (it + 2 < nit) {
        int s2 = cur + 2; if (s2 >= NBUF) s2 -= NBUF;
        STAGE2(s2, (it + 2) * 32);
      }

#pragma unroll
      for (int nf = 0; nf < 4; ++nf) {
        const int rb = (nf * 16 + lr) * 32;
        bf16x8 bf = pk8(*reinterpret_cast<const float4*>(&Bs[cur][rb + q0]),
                        *reinterpret_cast<const float4*>(&Bs[cur][rb + q1]));
#pragma unroll
        for (int mf = 0; mf < 3; ++mf)
          if (mf < mfn)
            acc[mf][nf] = __builtin_amdgcn_mfma_f32_16x16x32_bf16(af[mf], bf, acc[mf][nf], 0, 0, 0);
      }
      ++cur; if (cur >= NBUF) cur -= NBUF;
    }

#pragma unroll
    for (int mf = 0; mf < 3; ++mf) {
#pragma unroll
      for (int r = 0; r < 4; ++r) {
        const int mrow = m0 + wm + mf * 16 + kg * 4 + r;
        if (mrow < count) {
          const float cf = coef[off + mrow];
          float* prow = part + ((size_t)ks * A_ + off + mrow) * D_;
#pragma unroll
          for (int nf = 0; nf < 4; ++nf)
            prow[dbase + nf * 16 + lr] = cf * acc[mf][nf][r];
        }
      }
    }
    __syncthreads();
  }
}

// out[t] = sum over (ksn x 2 slots) partials in fixed order -> deterministic
__global__ void moe_combine(const float* __restrict__ part,
                            const int* __restrict__ slotof,
                            float* __restrict__ out,
                            int ksn) {
  const int t = blockIdx.x;
  const int i = threadIdx.x;  // 256 threads, float4 each
  const int g0 = slotof[2 * t], g1 = slotof[2 * t + 1];
  float4 o = make_float4(0.f, 0.f, 0.f, 0.f);
  for (int ks = 0; ks < ksn; ++ks) {
    const float* p = part + (size_t)ks * A_ * D_;
    float4 a = reinterpret_cast<const float4*>(p + (size_t)g0 * D_)[i];
    float4 b = reinterpret_cast<const float4*>(p + (size_t)g1 * D_)[i];
    o.x += a.x + b.x; o.y += a.y + b.y; o.z += a.z + b.z; o.w += a.w + b.w;
  }
  reinterpret_cast<float4*>(out + (size_t)t * D_)[i] = o;
}

extern "C" void kernel_launch(void* const* d_in, const int* in_sizes, int n_in,
                              void* d_out, int out_size, void* d_ws, size_t ws_size,
                              hipStream_t stream) {
  const float* x  = (const float*)d_in[0];
  const float* gw = (const float*)d_in[1];
  const float* w1 = (const float*)d_in[2];
  const float* w3 = (const float*)d_in[3];
  const float* w2 = (const float*)d_in[4];
  float* out = (float*)d_out;

  char* ws = (char*)d_ws;
  const size_t SM   = 32768;
  const size_t ACT  = (size_t)A_ * H_ * 2;   // 8 MB bf16
  const size_t XB   = (size_t)T_ * D_ * 2;   // 1 MB bf16
  const size_t P1   = (size_t)A_ * D_ * 4;   // 4 MB fp32 per K-split

  char* sm = ws;
  unsigned short* act = (unsigned short*)(ws + SM);
  unsigned short* xb  = (unsigned short*)(ws + SM + ACT);
  float* part         = (float*)(ws + SM + ACT + XB);
  const size_t base = SM + ACT + XB;
  const int ksn = (ws_size >= base + 8 * P1) ? 8 :
                  (ws_size >= base + 4 * P1) ? 4 :
                  (ws_size >= base + 2 * P1) ? 2 : 1;

  int*   sel     = (int*)  (sm);
  float* wtop    = (float*)(sm + 4096);
  int*   counts  = (int*)  (sm + 8192);
  int*   offsets = (int*)  (sm + 8192 + 64);
  int*   tokl    = (int*)  (sm + 12288);
  int*   slotof  = (int*)  (sm + 16384);
  float* coef    = (float*)(sm + 20480);

  moe_router <<<T_, 64, 0, stream>>>(x, gw, xb, sel, wtop);
  moe_compact<<<1, 512, 0, stream>>>(sel, wtop, counts, offsets, tokl, slotof, coef);
  moe_ffn1   <<<E_ * 64, 256, 0, stream>>>(xb, w1, w3, counts, offsets, tokl, act);
  moe_ffn2   <<<E_ * 16 * ksn, 256, 0, stream>>>(act, w2, counts, offsets, coef, part, H_ / ksn);
  moe_combine<<<T_, 256, 0, stream>>>(part, slotof, out, ksn);
}